// Round 8
// baseline (202.256 us; speedup 1.0000x reference)
//
#include <hip/hip_runtime.h>
#include <hip/hip_bf16.h>

typedef __attribute__((ext_vector_type(8))) short bf16x8;
typedef __attribute__((ext_vector_type(4))) float f32x4;

#define NH 16
#define DM 1024
#define HD 64
#define CSEQ 2048
#define MROWS 8192   // B*C
#define NBH 64       // B*NH

static __device__ __forceinline__ unsigned short f2bf(float f) {
  __hip_bfloat16 h = __float2bfloat16(f);
  return *reinterpret_cast<unsigned short*>(&h);
}

static __device__ __forceinline__ short bf_qscale(short s) {
  // fold attn scale (1/8) and log2(e) into Q: S*0.125*1.4427 -> exp2 domain
  unsigned u = ((unsigned)(unsigned short)s) << 16;
  float f = __builtin_bit_cast(float, u) * 0.18033688f;
  return (short)f2bf(f);
}

static __device__ __forceinline__ void gload_lds16(const void* g, void* l) {
  __builtin_amdgcn_global_load_lds(
      (const __attribute__((address_space(1))) unsigned int*)g,
      (__attribute__((address_space(3))) unsigned int*)l, 16, 0, 0);
}

// ---------------- cast fp32 -> bf16 (vectorized x4) ----------------
__global__ __launch_bounds__(256) void cast_f32_bf16(const float* __restrict__ in,
                                                     unsigned short* __restrict__ out,
                                                     int n4) {
  int stride = gridDim.x * blockDim.x;
  for (int i = blockIdx.x * blockDim.x + threadIdx.x; i < n4; i += stride) {
    float4 v = ((const float4*)in)[i];
    ushort4 o;
    o.x = f2bf(v.x); o.y = f2bf(v.y); o.z = f2bf(v.z); o.w = f2bf(v.w);
    ((ushort4*)out)[i] = o;
  }
}

// ---------------- transpose + cast: src[K][N] fp32 -> dst[N][K] bf16 ----------------
__global__ __launch_bounds__(256) void transpose_cast(const float* __restrict__ src,
                                                      unsigned short* __restrict__ dst,
                                                      int K, int N) {
  __shared__ float tile[32][33];
  int tx = threadIdx.x, ty = threadIdx.y;
  int n0 = blockIdx.x * 32, k0 = blockIdx.y * 32;
  #pragma unroll
  for (int i = 0; i < 32; i += 8)
    tile[ty + i][tx] = src[(size_t)(k0 + ty + i) * N + n0 + tx];
  __syncthreads();
  #pragma unroll
  for (int i = 0; i < 32; i += 8)
    dst[(size_t)(n0 + ty + i) * K + k0 + tx] = f2bf(tile[tx][ty + i]);
}

// ---------------- shared helpers ----------------
template<int CNT>
static __device__ __forceinline__ void ld_frags(const char* base, int r0, int cx, int g,
                                                bf16x8 (*out)[2]) {
  #pragma unroll
  for (int i = 0; i < CNT; i++) {
    int row = r0 + i * 16 + cx;
    #pragma unroll
    for (int kc = 0; kc < 2; kc++)
      out[i][kc] = *(const bf16x8*)(base + row * 128 + ((((kc << 2) | g) ^ (row & 7)) << 4));
  }
}

#define BARR() __builtin_amdgcn_s_barrier()
#define LGKM0() asm volatile("s_waitcnt lgkmcnt(0)" ::: "memory")
#define VMCNT8() asm volatile("s_waitcnt vmcnt(8)" ::: "memory")
#define VMCNT7() asm volatile("s_waitcnt vmcnt(7)" ::: "memory")
#define VMCNT0() asm volatile("s_waitcnt vmcnt(0)" ::: "memory")
#define PRIO1() __builtin_amdgcn_s_setprio(1)
#define PRIO0() __builtin_amdgcn_s_setprio(0)

// ---------------- MODE-1 scatter epilogue element (QKV) ----------------
static __device__ __forceinline__ void qkv_scatter(unsigned short* __restrict__ outQKV,
                                                   int rr, int col, float v) {
  int which = col >> 10, rem = col & 1023;
  int h = rem >> 6, d = rem & 63;
  int b = rr >> 11, cq = rr & 2047;
  if (which == 2) {
    // V: store transposed + kappa-permuted (pure within-32 permutation)
    int pos = (cq & ~31) + (((cq >> 2) & 3) << 3) + (((cq >> 4) & 1) << 2) + (cq & 3);
    outQKV[((size_t)2 * NBH + b * NH + h) * (CSEQ * HD) + (size_t)d * CSEQ + pos] = f2bf(v);
  } else {
    outQKV[((size_t)which * NBH + b * NH + h) * (CSEQ * HD) + (size_t)cq * HD + d] = f2bf(v);
  }
}

// ===================== 256x192 bf16 GEMM (QKV), 2 exact rounds =====================
// BM=256, BN=192, BK=64, 512 thr (8 waves as 2Mx4N, per-wave 128x48), 112KB LDS
// double-buffer -> 1 block/CU.  Geometry: 32x16 = 512 blocks = 2 exact rounds.
// vs 128^2: operand-panel L2 traffic per FLOP falls 1.71x ((BM+BN)/(BM*BN)),
// same 8 waves/CU TLP.  2-phase skeleton proven in gemm128d: P0 reads ALL
// frags (22 b128) -> mid-barrier seals buffer -> P1 stages t+2 into the
// retired buffer under the second MFMA half; boundary vmcnt(7) keeps t+2's
// 7 loads in flight (0 only at the final boundary).
__global__ __launch_bounds__(512, 2) void gemm_qkv(const unsigned short* __restrict__ A,
                                                   const unsigned short* __restrict__ BT,
                                                   const float* __restrict__ bias,
                                                   unsigned short* __restrict__ outQKV,
                                                   int N, int K) {
  __shared__ char sA[2][32768];   // [256 rows][64 k] bf16, rows 128B, slot^(row&7) swizzle
  __shared__ char sB[2][24576];   // [192 rows][64 k]
  int tid = threadIdx.x;
  int w = tid >> 6, l = tid & 63, g = l >> 4, cx = l & 15;
  int wm = (w >> 2) * 128, wn = (w & 3) * 48;

  // XCD-aware bijective swizzle (nwg = 512, %8 == 0)
  int nwgx = gridDim.x;                       // 16 col-tiles
  int nwg = nwgx * gridDim.y;                 // 512
  int gid = blockIdx.y * nwgx + blockIdx.x;
  int swz = (gid & 7) * (nwg >> 3) + (gid >> 3);
  int bm = (swz / nwgx) * 256, bn = (swz % nwgx) * 192;

  // staging: pre-swizzled global source, linear LDS dest.
  // A tile 32KB = 2048 chunks (4/thread); B tile 24KB = 1536 chunks (3/thread).
  const unsigned short* Ap[4];
  const unsigned short* Bp[3];
  #pragma unroll
  for (int i = 0; i < 4; i++) {
    int c = tid + i * 512;
    int ar = c >> 3, as = ((c & 7) ^ (ar & 7)) * 8;
    Ap[i] = A + (size_t)(bm + ar) * K + as;
  }
  #pragma unroll
  for (int i = 0; i < 3; i++) {
    int c = tid + i * 512;
    int br = c >> 3, bs = ((c & 7) ^ (br & 7)) * 8;
    Bp[i] = BT + (size_t)(bn + br) * K + bs;
  }

  #define STAGE_Q(t, buf) do { int ko_ = (t) << 6;                   \
      gload_lds16(Ap[0] + ko_, sA[buf] + (tid)        * 16);         \
      gload_lds16(Ap[1] + ko_, sA[buf] + (tid + 512)  * 16);         \
      gload_lds16(Ap[2] + ko_, sA[buf] + (tid + 1024) * 16);         \
      gload_lds16(Ap[3] + ko_, sA[buf] + (tid + 1536) * 16);         \
      gload_lds16(Bp[0] + ko_, sB[buf] + (tid)        * 16);         \
      gload_lds16(Bp[1] + ko_, sB[buf] + (tid + 512)  * 16);         \
      gload_lds16(Bp[2] + ko_, sB[buf] + (tid + 1024) * 16);         \
    } while (0)

  f32x4 acc[8][3];
  #pragma unroll
  for (int i = 0; i < 8; i++)
    #pragma unroll
    for (int j = 0; j < 3; j++) acc[i][j] = (f32x4){0.f, 0.f, 0.f, 0.f};

  int NT = K >> 6;   // 16

  STAGE_Q(0, 0);
  STAGE_Q(1, 1);
  VMCNT7();          // t0's 7 landed, t1's 7 in flight
  BARR();

  int cur = 0;
  for (int t = 0; t < NT; t++) {
    const char* Ac = sA[cur];
    const char* Bc = sB[cur];
    bool h1 = (t + 1) < NT, h2 = (t + 2) < NT;
    bf16x8 af[8][2], bfr[3][2];

    // ---- P0: ALL frag reads (16 A + 6 B = 22 b128); MFMA m0..3 ----
    ld_frags<8>(Ac, wm, cx, g, af);
    ld_frags<3>(Bc, wn, cx, g, bfr);
    BARR(); LGKM0();
    PRIO1();
    #pragma unroll
    for (int kc = 0; kc < 2; kc++)
      #pragma unroll
      for (int mi = 0; mi < 4; mi++)
        #pragma unroll
        for (int ni = 0; ni < 3; ni++)
          acc[mi][ni] = __builtin_amdgcn_mfma_f32_16x16x32_bf16(
              af[mi][kc], bfr[ni][kc], acc[mi][ni], 0, 0, 0);
    PRIO0();
    BARR();
    // sA[cur]/sB[cur] fully consumed by every wave at this point

    // ---- P1: stage t+2 into the retired buffer; MFMA m4..7 ----
    if (h2) STAGE_Q(t + 2, cur);
    PRIO1();
    #pragma unroll
    for (int kc = 0; kc < 2; kc++)
      #pragma unroll
      for (int mi = 4; mi < 8; mi++)
        #pragma unroll
        for (int ni = 0; ni < 3; ni++)
          acc[mi][ni] = __builtin_amdgcn_mfma_f32_16x16x32_bf16(
              af[mi][kc], bfr[ni][kc], acc[mi][ni], 0, 0, 0);
    PRIO0();
    if (h2)      { VMCNT7(); }   // t+1 landed; t+2's 7 stay in flight
    else if (h1) { VMCNT0(); }   // final boundary only
    BARR();
    cur ^= 1;
  }

  // epilogue: C/D layout row=(l>>4)*4+r (m-side), col=l&15 (n-side)
  #pragma unroll
  for (int mi = 0; mi < 8; mi++) {
    #pragma unroll
    for (int ni = 0; ni < 3; ni++) {
      int col = bn + wn + ni * 16 + cx;
      float bv = bias[col];
      int row0 = bm + wm + mi * 16 + g * 4;
      #pragma unroll
      for (int r = 0; r < 4; r++)
        qkv_scatter(outQKV, row0 + r, col, acc[mi][ni][r] + bv);
    }
  }
  #undef STAGE_Q
}

// ===================== 128x128 bf16 GEMM, 2 blocks/CU (proj) =====================
static __device__ __forceinline__ void mfma_pair(const bf16x8 af[4][2], const bf16x8 bf2[2][2],
                                                 f32x4 acc[4][4], int n0) {
  #pragma unroll
  for (int kc = 0; kc < 2; kc++)
    #pragma unroll
    for (int mi = 0; mi < 4; mi++)
      #pragma unroll
      for (int ni = 0; ni < 2; ni++)
        acc[mi][n0 + ni] = __builtin_amdgcn_mfma_f32_16x16x32_bf16(
            af[mi][kc], bf2[ni][kc], acc[mi][n0 + ni], 0, 0, 0);
}

__global__ __launch_bounds__(256, 2) void gemm128d(const unsigned short* __restrict__ A,
                                                   const unsigned short* __restrict__ BT,
                                                   const float* __restrict__ bias,
                                                   float* __restrict__ outF,
                                                   int N, int K) {
  __shared__ char sA[2][16384];   // [128 rows][64 k] bf16, rows 128B, slot^(row&7) swizzle
  __shared__ char sB[2][16384];
  int tid = threadIdx.x;
  int w = tid >> 6, l = tid & 63, g = l >> 4, cx = l & 15;
  int wm = (w >> 1) * 64, wn = (w & 1) * 64;

  // XCD-aware bijective swizzle (nwg % 8 == 0: 512)
  int nwgx = gridDim.x;
  int nwg = nwgx * gridDim.y;
  int gid = blockIdx.y * nwgx + blockIdx.x;
  int swz = (gid & 7) * (nwg >> 3) + (gid >> 3);
  int bm = (swz / nwgx) * 128, bn = (swz % nwgx) * 128;

  const unsigned short* Ap[4];
  const unsigned short* Bp[4];
  #pragma unroll
  for (int i = 0; i < 4; i++) {
    int c = tid + i * 256;
    int ar = c >> 3, as = ((c & 7) ^ (ar & 7)) * 8;
    Ap[i] = A + (size_t)(bm + ar) * K + as;
    Bp[i] = BT + (size_t)(bn + ar) * K + as;
  }

  #define STAGE_AB(t, buf) do { int ko_ = (t) << 6;                 \
      gload_lds16(Ap[0] + ko_, sA[buf] + (tid)       * 16);         \
      gload_lds16(Ap[1] + ko_, sA[buf] + (tid + 256) * 16);         \
      gload_lds16(Ap[2] + ko_, sA[buf] + (tid + 512) * 16);         \
      gload_lds16(Ap[3] + ko_, sA[buf] + (tid + 768) * 16);         \
      gload_lds16(Bp[0] + ko_, sB[buf] + (tid)       * 16);         \
      gload_lds16(Bp[1] + ko_, sB[buf] + (tid + 256) * 16);         \
      gload_lds16(Bp[2] + ko_, sB[buf] + (tid + 512) * 16);         \
      gload_lds16(Bp[3] + ko_, sB[buf] + (tid + 768) * 16);         \
    } while (0)

  f32x4 acc[4][4];
  #pragma unroll
  for (int i = 0; i < 4; i++)
    #pragma unroll
    for (int j = 0; j < 4; j++) acc[i][j] = (f32x4){0.f, 0.f, 0.f, 0.f};

  int NT = K >> 6;

  STAGE_AB(0, 0);
  STAGE_AB(1, 1);
  VMCNT8();
  BARR();

  int cur = 0;
  for (int t = 0; t < NT; t++) {
    const char* Ac = sA[cur];
    const char* Bc = sB[cur];
    bool h1 = (t + 1) < NT, h2 = (t + 2) < NT;
    bf16x8 af[4][2], bfr[4][2];

    ld_frags<4>(Ac, wm, cx, g, af);
    ld_frags<4>(Bc, wn, cx, g, bfr);
    BARR(); LGKM0();
    PRIO1(); mfma_pair(af, &bfr[0], acc, 0); PRIO0();
    BARR();

    if (h2) STAGE_AB(t + 2, cur);
    PRIO1(); mfma_pair(af, &bfr[2], acc, 2); PRIO0();
    if (h2)      { VMCNT8(); }
    else if (h1) { VMCNT0(); }
    BARR();
    cur ^= 1;
  }

  #pragma unroll
  for (int mi = 0; mi < 4; mi++) {
    #pragma unroll
    for (int ni = 0; ni < 4; ni++) {
      int col = bn + wn + ni * 16 + cx;
      float bv = bias[col];
      int row0 = bm + wm + mi * 16 + g * 4;
      #pragma unroll
      for (int r = 0; r < 4; r++)
        outF[(size_t)(row0 + r) * N + col] = acc[mi][ni][r] + bv;
    }
  }
  #undef STAGE_AB
}

// ---------------- flash attention (causal), swapped-QK^T, register-P ----------------
// R7-verified: 8 waves x 16 q-rows (QBLK=128), KVBLK=128, dbuf, one barrier/iter,
// XCD-aware remap, exp2 softmax, defer-max, DMA staging, ones-MFMA denominator.
__global__ __launch_bounds__(512, 4) void attn_kernel(const unsigned short* __restrict__ Qb,
                                                      const unsigned short* __restrict__ Kb,
                                                      const unsigned short* __restrict__ VTb,
                                                      unsigned short* __restrict__ O) {
  __shared__ char sKb[2][16384]; // K [128 k][64 d] bf16: slot sp of row holds d-slot sp^(row&7)
  __shared__ char sVt[2][16384]; // V^T [64 d][128 pos] bf16: slot sp of row d holds pos-slot sp^(d&7)
  int tid = threadIdx.x;
  int w = tid >> 6, l = tid & 63, g = l >> 4, cx = l & 15;
  int gid = blockIdx.x;
  int bh = ((gid >> 7) << 3) | (gid & 7);
  int qt = 15 - ((gid >> 3) & 15);

  const unsigned short* Qp  = Qb  + (size_t)bh * CSEQ * HD;
  const unsigned short* Kp  = Kb  + (size_t)bh * CSEQ * HD;
  const unsigned short* VTp = VTb + (size_t)bh * CSEQ * HD;  // [64 d][2048 k']

  int qrow = qt * 128 + w * 16 + cx;
  bf16x8 qf[2];
  qf[0] = *(const bf16x8*)(Qp + (size_t)qrow * HD + g * 8);
  qf[1] = *(const bf16x8*)(Qp + (size_t)qrow * HD + 32 + g * 8);
  #pragma unroll
  for (int kc = 0; kc < 2; kc++)
    #pragma unroll
    for (int j = 0; j < 8; j++) qf[kc][j] = bf_qscale(qf[kc][j]);

  bf16x8 vones;
  #pragma unroll
  for (int j = 0; j < 8; j++) vones[j] = (short)0x3F80;   // bf16 1.0

  f32x4 o[4], osum;
  #pragma unroll
  for (int nf2 = 0; nf2 < 4; nf2++) o[nf2] = (f32x4){0.f, 0.f, 0.f, 0.f};
  osum = (f32x4){0.f, 0.f, 0.f, 0.f};
  float mrow = -INFINITY;

  int c0 = tid, c1 = tid + 512;
  int krow0 = c0 >> 3, ksl0 = (c0 & 7) ^ (krow0 & 7);
  int krow1 = c1 >> 3, ksl1 = (c1 & 7) ^ (krow1 & 7);
  int vd0 = c0 >> 4, vsl0 = (c0 & 15) ^ (vd0 & 7);
  int vd1 = c1 >> 4, vsl1 = (c1 & 15) ^ (vd1 & 7);
  const unsigned short* Ksrc0 = Kp + (size_t)krow0 * HD + ksl0 * 8;   // += kt*8192
  const unsigned short* Ksrc1 = Kp + (size_t)krow1 * HD + ksl1 * 8;
  const unsigned short* Vsrc0 = VTp + (size_t)vd0 * CSEQ + vsl0 * 8;  // += kt*128
  const unsigned short* Vsrc1 = VTp + (size_t)vd1 * CSEQ + vsl1 * 8;

  gload_lds16(Ksrc0, sKb[0] + c0 * 16);
  gload_lds16(Ksrc1, sKb[0] + c1 * 16);
  gload_lds16(Vsrc0, sVt[0] + c0 * 16);
  gload_lds16(Vsrc1, sVt[0] + c1 * 16);
  __syncthreads();
  int cur = 0;

  for (int kt = 0; kt <= qt; kt++) {
    if (kt < qt) {
      size_t ko = (size_t)(kt + 1) * 128 * HD;
      size_t vo = (size_t)(kt + 1) * 128;
      gload_lds16(Ksrc0 + ko, sKb[cur ^ 1] + c0 * 16);
      gload_lds16(Ksrc1 + ko, sKb[cur ^ 1] + c1 * 16);
      gload_lds16(Vsrc0 + vo, sVt[cur ^ 1] + c0 * 16);
      gload_lds16(Vsrc1 + vo, sVt[cur ^ 1] + c1 * 16);
    }
    const char* Kc = sKb[cur];
    const char* Vc = sVt[cur];

    f32x4 sacc[8];
    #pragma unroll
    for (int nf = 0; nf < 8; nf++) sacc[nf] = (f32x4){0.f, 0.f, 0.f, 0.f};
    __builtin_amdgcn_s_setprio(1);
    #pragma unroll
    for (int kc = 0; kc < 2; kc++) {
      #pragma unroll
      for (int nf = 0; nf < 8; nf++) {
        int row = nf * 16 + cx;
        bf16x8 kf = *(const bf16x8*)(Kc + row * 128 + ((((kc << 2) | g) ^ (row & 7)) << 4));
        sacc[nf] = __builtin_amdgcn_mfma_f32_16x16x32_bf16(kf, qf[kc], sacc[nf], 0, 0, 0);
      }
    }
    __builtin_amdgcn_s_setprio(0);

    if (kt == qt) {
      #pragma unroll
      for (int nf = 0; nf < 8; nf++)
        #pragma unroll
        for (int r = 0; r < 4; r++)
          if (nf * 16 + 4 * g + r > w * 16 + cx) sacc[nf][r] = -INFINITY;
    }
    float m8[8];
    #pragma unroll
    for (int nf = 0; nf < 8; nf++)
      m8[nf] = fmaxf(fmaxf(sacc[nf][0], sacc[nf][1]), fmaxf(sacc[nf][2], sacc[nf][3]));
    float mx = fmaxf(fmaxf(fmaxf(m8[0], m8[1]), fmaxf(m8[2], m8[3])),
                     fmaxf(fmaxf(m8[4], m8[5]), fmaxf(m8[6], m8[7])));
    mx = fmaxf(mx, __shfl_xor(mx, 16));
    mx = fmaxf(mx, __shfl_xor(mx, 32));

    if (!__all(mx - mrow <= 8.f)) {
      float mnew = fmaxf(mrow, mx);
      float alpha = __builtin_amdgcn_exp2f(mrow - mnew);
      mrow = mnew;
      #pragma unroll
      for (int r = 0; r < 4; r++) {
        float ar = __shfl(alpha, (l & 48) | ((l >> 2) & 12) | r);
        #pragma unroll
        for (int nf2 = 0; nf2 < 4; nf2++) o[nf2][r] *= ar;
        osum[r] *= ar;
      }
    }
    #pragma unroll
    for (int nf = 0; nf < 8; nf++)
      #pragma unroll
      for (int r = 0; r < 4; r++)
        sacc[nf][r] = __builtin_amdgcn_exp2f(sacc[nf][r] - mrow);

    bf16x8 pa[4];
    #pragma unroll
    for (int kc = 0; kc < 4; kc++) {
      #pragma unroll
      for (int j = 0; j < 4; j++) {
        pa[kc][j]     = (short)f2bf(sacc[2 * kc][j]);
        pa[kc][j + 4] = (short)f2bf(sacc[2 * kc + 1][j]);
      }
    }

    __builtin_amdgcn_s_setprio(1);
    #pragma unroll
    for (int kc = 0; kc < 4; kc++) {
      #pragma unroll
      for (int nf2 = 0; nf2 < 4; nf2++) {
        int d = nf2 * 16 + cx;
        bf16x8 vf = *(const bf16x8*)(Vc + ((d * 256 + (((kc << 2) | g) << 4)) ^ ((d & 7) << 4)));
        o[nf2] = __builtin_amdgcn_mfma_f32_16x16x32_bf16(pa[kc], vf, o[nf2], 0, 0, 0);
      }
      osum = __builtin_amdgcn_mfma_f32_16x16x32_bf16(pa[kc], vones, osum, 0, 0, 0);
    }
    __builtin_amdgcn_s_setprio(0);

    if (kt < qt) {
      __syncthreads();
      cur ^= 1;
    }
  }

  int b = bh >> 4, h = bh & 15;
  #pragma unroll
  for (int r = 0; r < 4; r++) {
    float inv = 1.0f / osum[r];
    int q = qt * 128 + w * 16 + 4 * g + r;
    size_t base = ((size_t)(b * CSEQ + q)) * DM + h * HD;
    #pragma unroll
    for (int nf2 = 0; nf2 < 4; nf2++)
      O[base + nf2 * 16 + cx] = f2bf(o[nf2][r] * inv);
  }
}

// ---------------- launch ----------------
extern "C" void kernel_launch(void* const* d_in, const int* in_sizes, int n_in,
                              void* d_out, int out_size, void* d_ws, size_t ws_size,
                              hipStream_t stream) {
  const float* x    = (const float*)d_in[0];
  const float* Wqkv = (const float*)d_in[1];
  const float* bqkv = (const float*)d_in[2];
  const float* Wo   = (const float*)d_in[3];
  const float* bo   = (const float*)d_in[4];
  float* out = (float*)d_out;

  unsigned short* ws = (unsigned short*)d_ws;
  const size_t XB_OFF    = 0;                     // x bf16 [8192][1024]
  const size_t WQKVT_OFF = 8388608;               // Wqkv^T bf16 [3072][1024]
  const size_t WOT_OFF   = WQKVT_OFF + 3145728;   // Wo^T bf16 [1024][1024]
  const size_t QKV_OFF   = WOT_OFF + 1048576;     // Q,K [bh][k][d]; V^T [bh][d][k']
  const size_t ATT_OFF   = QKV_OFF + 3 * 8388608; // att out bf16 [8192][1024]

  unsigned short* xb    = ws + XB_OFF;
  unsigned short* wqkvT = ws + WQKVT_OFF;
  unsigned short* woT   = ws + WOT_OFF;
  unsigned short* qkv   = ws + QKV_OFF;
  unsigned short* att   = ws + ATT_OFF;

  cast_f32_bf16<<<2048, 256, 0, stream>>>(x, xb, (MROWS * DM) / 4);
  transpose_cast<<<dim3(3 * DM / 32, DM / 32), dim3(32, 8), 0, stream>>>(Wqkv, wqkvT, DM, 3 * DM);
  transpose_cast<<<dim3(DM / 32, DM / 32), dim3(32, 8), 0, stream>>>(Wo, woT, DM, DM);

  // QKV: 256x192 tile, 1 block/CU, 32x16 = 512 blocks = 2 exact rounds
  gemm_qkv<<<dim3(3 * DM / 192, MROWS / 256), 512, 0, stream>>>(
      xb, wqkvT, bqkv, qkv, 3 * DM, DM);

  attn_kernel<<<dim3(1024), 512, 0, stream>>>(
      qkv, qkv + 8388608, qkv + 16777216, att);

  // proj: 128x128 2-blocks/CU (8x64 = 512 blocks, 1 exact round)
  gemm128d<<<dim3(DM / 128, MROWS / 128), 256, 0, stream>>>(
      att, woT, bo, out, DM, DM);
}

// Round 9
// 190.441 us; speedup vs baseline: 1.0620x; 1.0620x over previous
//
#include <hip/hip_runtime.h>
#include <hip/hip_bf16.h>

typedef __attribute__((ext_vector_type(8))) short bf16x8;
typedef __attribute__((ext_vector_type(4))) float f32x4;

#define NH 16
#define DM 1024
#define HD 64
#define CSEQ 2048
#define MROWS 8192   // B*C
#define NBH 64       // B*NH

static __device__ __forceinline__ unsigned short f2bf(float f) {
  __hip_bfloat16 h = __float2bfloat16(f);
  return *reinterpret_cast<unsigned short*>(&h);
}

static __device__ __forceinline__ short bf_qscale(short s) {
  // fold attn scale (1/8) and log2(e) into Q: S*0.125*1.4427 -> exp2 domain
  unsigned u = ((unsigned)(unsigned short)s) << 16;
  float f = __builtin_bit_cast(float, u) * 0.18033688f;
  return (short)f2bf(f);
}

static __device__ __forceinline__ void gload_lds16(const void* g, void* l) {
  __builtin_amdgcn_global_load_lds(
      (const __attribute__((address_space(1))) unsigned int*)g,
      (__attribute__((address_space(3))) unsigned int*)l, 16, 0, 0);
}

// ---------------- cast fp32 -> bf16 (vectorized x4) ----------------
__global__ __launch_bounds__(256) void cast_f32_bf16(const float* __restrict__ in,
                                                     unsigned short* __restrict__ out,
                                                     int n4) {
  int stride = gridDim.x * blockDim.x;
  for (int i = blockIdx.x * blockDim.x + threadIdx.x; i < n4; i += stride) {
    float4 v = ((const float4*)in)[i];
    ushort4 o;
    o.x = f2bf(v.x); o.y = f2bf(v.y); o.z = f2bf(v.z); o.w = f2bf(v.w);
    ((ushort4*)out)[i] = o;
  }
}

// ---------------- transpose + cast: src[K][N] fp32 -> dst[N][K] bf16 ----------------
__global__ __launch_bounds__(256) void transpose_cast(const float* __restrict__ src,
                                                      unsigned short* __restrict__ dst,
                                                      int K, int N) {
  __shared__ float tile[32][33];
  int tx = threadIdx.x, ty = threadIdx.y;
  int n0 = blockIdx.x * 32, k0 = blockIdx.y * 32;
  #pragma unroll
  for (int i = 0; i < 32; i += 8)
    tile[ty + i][tx] = src[(size_t)(k0 + ty + i) * N + n0 + tx];
  __syncthreads();
  #pragma unroll
  for (int i = 0; i < 32; i += 8)
    dst[(size_t)(n0 + ty + i) * K + k0 + tx] = f2bf(tile[tx][ty + i]);
}

// ---------------- shared helpers ----------------
template<int CNT>
static __device__ __forceinline__ void ld_frags(const char* base, int r0, int cx, int g,
                                                bf16x8 (*out)[2]) {
  #pragma unroll
  for (int i = 0; i < CNT; i++) {
    int row = r0 + i * 16 + cx;
    #pragma unroll
    for (int kc = 0; kc < 2; kc++)
      out[i][kc] = *(const bf16x8*)(base + row * 128 + ((((kc << 2) | g) ^ (row & 7)) << 4));
  }
}

#define BARR() __builtin_amdgcn_s_barrier()
#define LGKM0() asm volatile("s_waitcnt lgkmcnt(0)" ::: "memory")
#define VMCNT8() asm volatile("s_waitcnt vmcnt(8)" ::: "memory")
#define VMCNT0() asm volatile("s_waitcnt vmcnt(0)" ::: "memory")
#define PRIO1() __builtin_amdgcn_s_setprio(1)
#define PRIO0() __builtin_amdgcn_s_setprio(0)

// ===================== 128x128 bf16 GEMM, 2 blocks/CU, 2 barriers/tile =====================
// R3/R7-proven geometry (128^2, BK=64, 4 waves 2Mx2N, 64KB LDS dbuf, 2 blocks/CU),
// restructured from 3 to 2 barriers per K-tile:
//   reads -> lgkm0 (own frags in regs) -> BARR (=> every wave's frags in regs;
//   buffer cur is DEAD) -> stage t+2 into it -> 32 MFMA -> vmcnt(8) -> BARR.
// The stage-issue moves a half-tile earlier (full-tile issue-to-deadline window)
// and the MFMA halves merge into one setprio cluster.
// MODE 0: write fp32 out[M][N].
// MODE 1: scatter bf16 into Q,K [bh][cq][d]; V transposed+kappa-permuted.
static __device__ __forceinline__ void mfma_all(const bf16x8 af[4][2], const bf16x8 bfr[4][2],
                                                f32x4 acc[4][4]) {
  #pragma unroll
  for (int kc = 0; kc < 2; kc++)
    #pragma unroll
    for (int mi = 0; mi < 4; mi++)
      #pragma unroll
      for (int ni = 0; ni < 4; ni++)
        acc[mi][ni] = __builtin_amdgcn_mfma_f32_16x16x32_bf16(
            af[mi][kc], bfr[ni][kc], acc[mi][ni], 0, 0, 0);
}

template<int MODE>
__global__ __launch_bounds__(256, 2) void gemm128d(const unsigned short* __restrict__ A,
                                                   const unsigned short* __restrict__ BT,
                                                   const float* __restrict__ bias,
                                                   float* __restrict__ outF,
                                                   unsigned short* __restrict__ outQKV,
                                                   int N, int K) {
  __shared__ char sA[2][16384];   // [128 rows][64 k] bf16, rows 128B, slot^(row&7) swizzle
  __shared__ char sB[2][16384];
  int tid = threadIdx.x;
  int w = tid >> 6, l = tid & 63, g = l >> 4, cx = l & 15;
  int wm = (w >> 1) * 64, wn = (w & 1) * 64;

  // XCD-aware bijective swizzle (nwg % 8 == 0: 1536 and 512)
  int nwgx = gridDim.x;
  int nwg = nwgx * gridDim.y;
  int gid = blockIdx.y * nwgx + blockIdx.x;
  int swz = (gid & 7) * (nwg >> 3) + (gid >> 3);
  int bm = (swz / nwgx) * 128, bn = (swz % nwgx) * 128;

  const unsigned short* Ap[4];
  const unsigned short* Bp[4];
  #pragma unroll
  for (int i = 0; i < 4; i++) {
    int c = tid + i * 256;
    int ar = c >> 3, as = ((c & 7) ^ (ar & 7)) * 8;
    Ap[i] = A + (size_t)(bm + ar) * K + as;
    Bp[i] = BT + (size_t)(bn + ar) * K + as;
  }

  #define STAGE_AB(t, buf) do { int ko_ = (t) << 6;                 \
      gload_lds16(Ap[0] + ko_, sA[buf] + (tid)       * 16);         \
      gload_lds16(Ap[1] + ko_, sA[buf] + (tid + 256) * 16);         \
      gload_lds16(Ap[2] + ko_, sA[buf] + (tid + 512) * 16);         \
      gload_lds16(Ap[3] + ko_, sA[buf] + (tid + 768) * 16);         \
      gload_lds16(Bp[0] + ko_, sB[buf] + (tid)       * 16);         \
      gload_lds16(Bp[1] + ko_, sB[buf] + (tid + 256) * 16);         \
      gload_lds16(Bp[2] + ko_, sB[buf] + (tid + 512) * 16);         \
      gload_lds16(Bp[3] + ko_, sB[buf] + (tid + 768) * 16);         \
    } while (0)

  f32x4 acc[4][4];
  #pragma unroll
  for (int i = 0; i < 4; i++)
    #pragma unroll
    for (int j = 0; j < 4; j++) acc[i][j] = (f32x4){0.f, 0.f, 0.f, 0.f};

  int NT = K >> 6;

  // prologue: t0 -> buf0, t1 -> buf1 (t1's 8 stay in flight)
  STAGE_AB(0, 0);
  STAGE_AB(1, 1);
  VMCNT8();
  BARR();

  int cur = 0;
  for (int t = 0; t < NT; t++) {
    const char* Ac = sA[cur];
    const char* Bc = sB[cur];
    bool h1 = (t + 1) < NT, h2 = (t + 2) < NT;
    bf16x8 af[4][2], bfr[4][2];

    // all 16 frag reads, then wait them into registers
    ld_frags<4>(Ac, wm, cx, g, af);
    ld_frags<4>(Bc, wn, cx, g, bfr);
    LGKM0();
    BARR();   // every wave's frags now in regs -> buffer cur is dead

    // stage t+2 into the dead buffer; full-tile window to its vmcnt deadline
    if (h2) STAGE_AB(t + 2, cur);

    PRIO1(); mfma_all(af, bfr, acc); PRIO0();

    if (h2)      { VMCNT8(); }   // t+1's 8 landed; t+2's 8 stay in flight
    else if (h1) { VMCNT0(); }   // final boundary only
    BARR();
    cur ^= 1;
  }

  // epilogue: C/D layout row=(l>>4)*4+r (m-side), col=l&15 (n-side)
  #pragma unroll
  for (int mi = 0; mi < 4; mi++) {
    #pragma unroll
    for (int ni = 0; ni < 4; ni++) {
      int col = bn + wn + ni * 16 + cx;
      float bv = bias[col];
      int row0 = bm + wm + mi * 16 + g * 4;
      #pragma unroll
      for (int r = 0; r < 4; r++) {
        float v = acc[mi][ni][r] + bv;
        int rr = row0 + r;
        if (MODE == 0) {
          outF[(size_t)rr * N + col] = v;
        } else {
          int which = col >> 10, rem = col & 1023;
          int h = rem >> 6, d = rem & 63;
          int b = rr >> 11, cq = rr & 2047;
          if (which == 2) {
            // V: store transposed + kappa-permuted (pure within-32 permutation)
            int pos = (cq & ~31) + (((cq >> 2) & 3) << 3) + (((cq >> 4) & 1) << 2) + (cq & 3);
            outQKV[((size_t)2 * NBH + b * NH + h) * (CSEQ * HD) +
                   (size_t)d * CSEQ + pos] = f2bf(v);
          } else {
            outQKV[((size_t)which * NBH + b * NH + h) * (CSEQ * HD) + (size_t)cq * HD + d] = f2bf(v);
          }
        }
      }
    }
  }
  #undef STAGE_AB
}

// ---------------- flash attention (causal), swapped-QK^T, register-P ----------------
// R7-verified: 8 waves x 16 q-rows (QBLK=128), KVBLK=128, dbuf, one barrier/iter,
// XCD-aware remap, exp2 softmax, defer-max, DMA staging, ones-MFMA denominator.
__global__ __launch_bounds__(512, 4) void attn_kernel(const unsigned short* __restrict__ Qb,
                                                      const unsigned short* __restrict__ Kb,
                                                      const unsigned short* __restrict__ VTb,
                                                      unsigned short* __restrict__ O) {
  __shared__ char sKb[2][16384]; // K [128 k][64 d] bf16: slot sp of row holds d-slot sp^(row&7)
  __shared__ char sVt[2][16384]; // V^T [64 d][128 pos] bf16: slot sp of row d holds pos-slot sp^(d&7)
  int tid = threadIdx.x;
  int w = tid >> 6, l = tid & 63, g = l >> 4, cx = l & 15;
  int gid = blockIdx.x;
  int bh = ((gid >> 7) << 3) | (gid & 7);
  int qt = 15 - ((gid >> 3) & 15);

  const unsigned short* Qp  = Qb  + (size_t)bh * CSEQ * HD;
  const unsigned short* Kp  = Kb  + (size_t)bh * CSEQ * HD;
  const unsigned short* VTp = VTb + (size_t)bh * CSEQ * HD;  // [64 d][2048 k']

  int qrow = qt * 128 + w * 16 + cx;
  bf16x8 qf[2];
  qf[0] = *(const bf16x8*)(Qp + (size_t)qrow * HD + g * 8);
  qf[1] = *(const bf16x8*)(Qp + (size_t)qrow * HD + 32 + g * 8);
  #pragma unroll
  for (int kc = 0; kc < 2; kc++)
    #pragma unroll
    for (int j = 0; j < 8; j++) qf[kc][j] = bf_qscale(qf[kc][j]);

  bf16x8 vones;
  #pragma unroll
  for (int j = 0; j < 8; j++) vones[j] = (short)0x3F80;   // bf16 1.0

  f32x4 o[4], osum;
  #pragma unroll
  for (int nf2 = 0; nf2 < 4; nf2++) o[nf2] = (f32x4){0.f, 0.f, 0.f, 0.f};
  osum = (f32x4){0.f, 0.f, 0.f, 0.f};
  float mrow = -INFINITY;

  int c0 = tid, c1 = tid + 512;
  int krow0 = c0 >> 3, ksl0 = (c0 & 7) ^ (krow0 & 7);
  int krow1 = c1 >> 3, ksl1 = (c1 & 7) ^ (krow1 & 7);
  int vd0 = c0 >> 4, vsl0 = (c0 & 15) ^ (vd0 & 7);
  int vd1 = c1 >> 4, vsl1 = (c1 & 15) ^ (vd1 & 7);
  const unsigned short* Ksrc0 = Kp + (size_t)krow0 * HD + ksl0 * 8;   // += kt*8192
  const unsigned short* Ksrc1 = Kp + (size_t)krow1 * HD + ksl1 * 8;
  const unsigned short* Vsrc0 = VTp + (size_t)vd0 * CSEQ + vsl0 * 8;  // += kt*128
  const unsigned short* Vsrc1 = VTp + (size_t)vd1 * CSEQ + vsl1 * 8;

  gload_lds16(Ksrc0, sKb[0] + c0 * 16);
  gload_lds16(Ksrc1, sKb[0] + c1 * 16);
  gload_lds16(Vsrc0, sVt[0] + c0 * 16);
  gload_lds16(Vsrc1, sVt[0] + c1 * 16);
  __syncthreads();
  int cur = 0;

  for (int kt = 0; kt <= qt; kt++) {
    if (kt < qt) {
      size_t ko = (size_t)(kt + 1) * 128 * HD;
      size_t vo = (size_t)(kt + 1) * 128;
      gload_lds16(Ksrc0 + ko, sKb[cur ^ 1] + c0 * 16);
      gload_lds16(Ksrc1 + ko, sKb[cur ^ 1] + c1 * 16);
      gload_lds16(Vsrc0 + vo, sVt[cur ^ 1] + c0 * 16);
      gload_lds16(Vsrc1 + vo, sVt[cur ^ 1] + c1 * 16);
    }
    const char* Kc = sKb[cur];
    const char* Vc = sVt[cur];

    f32x4 sacc[8];
    #pragma unroll
    for (int nf = 0; nf < 8; nf++) sacc[nf] = (f32x4){0.f, 0.f, 0.f, 0.f};
    __builtin_amdgcn_s_setprio(1);
    #pragma unroll
    for (int kc = 0; kc < 2; kc++) {
      #pragma unroll
      for (int nf = 0; nf < 8; nf++) {
        int row = nf * 16 + cx;
        bf16x8 kf = *(const bf16x8*)(Kc + row * 128 + ((((kc << 2) | g) ^ (row & 7)) << 4));
        sacc[nf] = __builtin_amdgcn_mfma_f32_16x16x32_bf16(kf, qf[kc], sacc[nf], 0, 0, 0);
      }
    }
    __builtin_amdgcn_s_setprio(0);

    if (kt == qt) {
      #pragma unroll
      for (int nf = 0; nf < 8; nf++)
        #pragma unroll
        for (int r = 0; r < 4; r++)
          if (nf * 16 + 4 * g + r > w * 16 + cx) sacc[nf][r] = -INFINITY;
    }
    float m8[8];
    #pragma unroll
    for (int nf = 0; nf < 8; nf++)
      m8[nf] = fmaxf(fmaxf(sacc[nf][0], sacc[nf][1]), fmaxf(sacc[nf][2], sacc[nf][3]));
    float mx = fmaxf(fmaxf(fmaxf(m8[0], m8[1]), fmaxf(m8[2], m8[3])),
                     fmaxf(fmaxf(m8[4], m8[5]), fmaxf(m8[6], m8[7])));
    mx = fmaxf(mx, __shfl_xor(mx, 16));
    mx = fmaxf(mx, __shfl_xor(mx, 32));

    if (!__all(mx - mrow <= 8.f)) {
      float mnew = fmaxf(mrow, mx);
      float alpha = __builtin_amdgcn_exp2f(mrow - mnew);
      mrow = mnew;
      #pragma unroll
      for (int r = 0; r < 4; r++) {
        float ar = __shfl(alpha, (l & 48) | ((l >> 2) & 12) | r);
        #pragma unroll
        for (int nf2 = 0; nf2 < 4; nf2++) o[nf2][r] *= ar;
        osum[r] *= ar;
      }
    }
    #pragma unroll
    for (int nf = 0; nf < 8; nf++)
      #pragma unroll
      for (int r = 0; r < 4; r++)
        sacc[nf][r] = __builtin_amdgcn_exp2f(sacc[nf][r] - mrow);

    bf16x8 pa[4];
    #pragma unroll
    for (int kc = 0; kc < 4; kc++) {
      #pragma unroll
      for (int j = 0; j < 4; j++) {
        pa[kc][j]     = (short)f2bf(sacc[2 * kc][j]);
        pa[kc][j + 4] = (short)f2bf(sacc[2 * kc + 1][j]);
      }
    }

    __builtin_amdgcn_s_setprio(1);
    #pragma unroll
    for (int kc = 0; kc < 4; kc++) {
      #pragma unroll
      for (int nf2 = 0; nf2 < 4; nf2++) {
        int d = nf2 * 16 + cx;
        bf16x8 vf = *(const bf16x8*)(Vc + ((d * 256 + (((kc << 2) | g) << 4)) ^ ((d & 7) << 4)));
        o[nf2] = __builtin_amdgcn_mfma_f32_16x16x32_bf16(pa[kc], vf, o[nf2], 0, 0, 0);
      }
      osum = __builtin_amdgcn_mfma_f32_16x16x32_bf16(pa[kc], vones, osum, 0, 0, 0);
    }
    __builtin_amdgcn_s_setprio(0);

    if (kt < qt) {
      __syncthreads();
      cur ^= 1;
    }
  }

  int b = bh >> 4, h = bh & 15;
  #pragma unroll
  for (int r = 0; r < 4; r++) {
    float inv = 1.0f / osum[r];
    int q = qt * 128 + w * 16 + 4 * g + r;
    size_t base = ((size_t)(b * CSEQ + q)) * DM + h * HD;
    #pragma unroll
    for (int nf2 = 0; nf2 < 4; nf2++)
      O[base + nf2 * 16 + cx] = f2bf(o[nf2][r] * inv);
  }
}

// ---------------- launch ----------------
extern "C" void kernel_launch(void* const* d_in, const int* in_sizes, int n_in,
                              void* d_out, int out_size, void* d_ws, size_t ws_size,
                              hipStream_t stream) {
  const float* x    = (const float*)d_in[0];
  const float* Wqkv = (const float*)d_in[1];
  const float* bqkv = (const float*)d_in[2];
  const float* Wo   = (const float*)d_in[3];
  const float* bo   = (const float*)d_in[4];
  float* out = (float*)d_out;

  unsigned short* ws = (unsigned short*)d_ws;
  const size_t XB_OFF    = 0;                     // x bf16 [8192][1024]
  const size_t WQKVT_OFF = 8388608;               // Wqkv^T bf16 [3072][1024]
  const size_t WOT_OFF   = WQKVT_OFF + 3145728;   // Wo^T bf16 [1024][1024]
  const size_t QKV_OFF   = WOT_OFF + 1048576;     // Q,K [bh][k][d]; V^T [bh][d][k']
  const size_t ATT_OFF   = QKV_OFF + 3 * 8388608; // att out bf16 [8192][1024]

  unsigned short* xb    = ws + XB_OFF;
  unsigned short* wqkvT = ws + WQKVT_OFF;
  unsigned short* woT   = ws + WOT_OFF;
  unsigned short* qkv   = ws + QKV_OFF;
  unsigned short* att   = ws + ATT_OFF;

  cast_f32_bf16<<<2048, 256, 0, stream>>>(x, xb, (MROWS * DM) / 4);
  transpose_cast<<<dim3(3 * DM / 32, DM / 32), dim3(32, 8), 0, stream>>>(Wqkv, wqkvT, DM, 3 * DM);
  transpose_cast<<<dim3(DM / 32, DM / 32), dim3(32, 8), 0, stream>>>(Wo, woT, DM, DM);

  // 128x128 tile, 2 blocks/CU: QKV 24x64 = 1536 blocks (3 rounds of 512),
  // proj 8x64 = 512 blocks (1 exact round)
  gemm128d<1><<<dim3(3 * DM / 128, MROWS / 128), 256, 0, stream>>>(
      xb, wqkvT, bqkv, nullptr, qkv, 3 * DM, DM);

  attn_kernel<<<dim3(1024), 512, 0, stream>>>(
      qkv, qkv + 8388608, qkv + 16777216, att);

  gemm128d<0><<<dim3(DM / 128, MROWS / 128), 256, 0, stream>>>(
      att, woT, bo, out, nullptr, DM, DM);
}